// Round 3
// baseline (512.879 us; speedup 1.0000x reference)
//
#include <hip/hip_runtime.h>
#include <math.h>

#define CD 512
#define NNODE 64
#define TPAD 520   // bf16 tile row stride: 1040 B, measured 0 bank conflicts

typedef __attribute__((ext_vector_type(8)))  short bfrag8;   // 8 bf16 (4 VGPRs)
typedef __attribute__((ext_vector_type(8)))  short sv8;
typedef __attribute__((ext_vector_type(4)))  short sv4;
typedef __attribute__((ext_vector_type(16))) float f32x16;

__device__ __forceinline__ unsigned short f2bf(float f) {
    union { float f; unsigned u; } v; v.f = f;
    unsigned r = (v.u + 0x7fffu + ((v.u >> 16) & 1u)) >> 16;
    return (unsigned short)r;
}
__device__ __forceinline__ float bf2f(unsigned short u) {
    union { unsigned u; float f; } v; v.u = ((unsigned)u) << 16;
    return v.f;
}

// ---- pack 10 weights into 32x32x16 MFMA-B fragment order ----
// Bp[kt(32)][g(16)][lane][i(8)] = W[c=g*32+(l&31)][k=kt*16+(l>>5)*8+i]
__global__ void pack32_k(const float* __restrict__ W0, const float* __restrict__ W1,
                         const float* __restrict__ W2, const float* __restrict__ W3,
                         const float* __restrict__ W4, const float* __restrict__ W5,
                         const float* __restrict__ W6, const float* __restrict__ W7,
                         const float* __restrict__ W8, const float* __restrict__ W9,
                         unsigned short* __restrict__ out)
{
    const float* Ws[10] = {W0,W1,W2,W3,W4,W5,W6,W7,W8,W9};
    int kt = blockIdx.x, ct = blockIdx.y, wi = blockIdx.z, l = threadIdx.x;
    const float* W = Ws[wi];
    int c  = ct * 32 + (l & 31);
    int k0 = kt * 16 + (l >> 5) * 8;
    const float* src = W + (size_t)c * CD + k0;
    unsigned short o[8];
    #pragma unroll
    for (int i = 0; i < 8; ++i) o[i] = f2bf(src[i]);
    unsigned short* dst = out + (size_t)wi * 262144 + ((size_t)(kt * 16 + ct) * 64 + l) * 8;
    *(bfrag8*)dst = *(bfrag8*)o;
}

// ---- projection: O = A(1024x512) @ W.T, M=32 tile per block ----
// FUSE: stage computes x1 = relu(res + LN(A + agg)) on the fly (A = XU),
// feeds bf16 x1 to the GEMM, and widx==0 writes f32 x1 for later use.
template<bool FUSE>
__global__ __launch_bounds__(512, 4) void proj_mfma(
    const float* __restrict__ A, const unsigned short* __restrict__ Bp4,
    float* __restrict__ O0, float* __restrict__ O1,
    float* __restrict__ O2, float* __restrict__ O3,
    const float* __restrict__ aggp, const float* __restrict__ xres,
    const float* __restrict__ gvp, const float* __restrict__ bvp,
    float* __restrict__ x1out)
{
    __shared__ unsigned short tile[32 * TPAD];
    const int rb = blockIdx.x * 32, widx = blockIdx.y;
    float* outs[4] = {O0,O1,O2,O3};
    float* out = outs[widx];
    const unsigned short* Bp = Bp4 + (size_t)widx * 262144;
    const int t = threadIdx.x, l = t & 63, w = t >> 6;

    if (FUSE) {
        // one row per 16-thread group; 32 channels per thread
        const int r32 = t >> 4, sub = t & 15, cb = sub * 32;
        const size_t rowo = (size_t)(rb + r32) * CD + cb;
        const float* xu = A + rowo;
        const float* ag = aggp + rowo;
        float v[32]; float s1 = 0.f, s2 = 0.f;
        #pragma unroll
        for (int q = 0; q < 8; ++q) {
            float4 a4 = *(const float4*)(xu + q * 4);
            float4 g4 = *(const float4*)(ag + q * 4);
            float v0 = a4.x + g4.x, v1 = a4.y + g4.y;
            float v2 = a4.z + g4.z, v3 = a4.w + g4.w;
            v[q*4+0] = v0; v[q*4+1] = v1; v[q*4+2] = v2; v[q*4+3] = v3;
            s1 += v0 + v1 + v2 + v3;
            s2 += v0*v0 + v1*v1 + v2*v2 + v3*v3;
        }
        #pragma unroll
        for (int off = 1; off < 16; off <<= 1) {
            s1 += __shfl_xor(s1, off, 64);
            s2 += __shfl_xor(s2, off, 64);
        }
        float mean = s1 * (1.f / 512.f);
        float var  = s2 * (1.f / 512.f) - mean * mean;
        float rs   = rsqrtf(var + 1e-5f);
        const float* rr = xres + rowo;
        unsigned short* trow = tile + r32 * TPAD + cb;
        float* xo = x1out + rowo;
        #pragma unroll
        for (int q = 0; q < 8; ++q) {
            float4 r4 = *(const float4*)(rr + q * 4);
            float4 g4 = *(const float4*)(gvp + cb + q * 4);
            float4 b4 = *(const float4*)(bvp + cb + q * 4);
            float x0 = fmaxf(r4.x + (v[q*4+0]-mean)*rs*g4.x + b4.x, 0.f);
            float x1_ = fmaxf(r4.y + (v[q*4+1]-mean)*rs*g4.y + b4.y, 0.f);
            float x2 = fmaxf(r4.z + (v[q*4+2]-mean)*rs*g4.z + b4.z, 0.f);
            float x3 = fmaxf(r4.w + (v[q*4+3]-mean)*rs*g4.w + b4.w, 0.f);
            sv4 pk; pk.x = (short)f2bf(x0); pk.y = (short)f2bf(x1_);
            pk.z = (short)f2bf(x2); pk.w = (short)f2bf(x3);
            *(sv4*)(trow + q * 4) = pk;
            if (widx == 0) {
                float4 o4; o4.x = x0; o4.y = x1_; o4.z = x2; o4.w = x3;
                *(float4*)(xo + q * 4) = o4;
            }
        }
    } else {
        const float* src = A + (size_t)rb * CD;
        #pragma unroll 4
        for (int it = 0; it < 8; ++it) {
            int flat = it * 2048 + t * 4;
            float4 v4 = *(const float4*)(src + flat);
            int r = flat >> 9, c = flat & 511;
            sv4 pk; pk.x = (short)f2bf(v4.x); pk.y = (short)f2bf(v4.y);
            pk.z = (short)f2bf(v4.z); pk.w = (short)f2bf(v4.w);
            *(sv4*)(tile + r * TPAD + c) = pk;
        }
    }
    __syncthreads();

    f32x16 acc[2] = {};
    const unsigned short* aptr = tile + (size_t)(l & 31) * TPAD + (l >> 5) * 8;
    const unsigned short* bptr = Bp + ((size_t)(2 * w) * 64 + l) * 8;

    bfrag8 a0, a1, b0[2], b1[2];
    a0 = *(const bfrag8*)aptr;
    #pragma unroll
    for (int ct = 0; ct < 2; ++ct) b0[ct] = *(const bfrag8*)(bptr + ct * 512);
    for (int k2 = 0; k2 < 16; ++k2) {
        int kt1 = 2 * k2 + 1;
        a1 = *(const bfrag8*)(aptr + kt1 * 16);
        #pragma unroll
        for (int ct = 0; ct < 2; ++ct) b1[ct] = *(const bfrag8*)(bptr + (size_t)kt1 * 8192 + ct * 512);
        #pragma unroll
        for (int ct = 0; ct < 2; ++ct)
            acc[ct] = __builtin_amdgcn_mfma_f32_32x32x16_bf16(a0, b0[ct], acc[ct], 0, 0, 0);
        int kt2 = (k2 == 15) ? 31 : (2 * k2 + 2);
        a0 = *(const bfrag8*)(aptr + kt2 * 16);
        #pragma unroll
        for (int ct = 0; ct < 2; ++ct) b0[ct] = *(const bfrag8*)(bptr + (size_t)kt2 * 8192 + ct * 512);
        #pragma unroll
        for (int ct = 0; ct < 2; ++ct)
            acc[ct] = __builtin_amdgcn_mfma_f32_32x32x16_bf16(a1, b1[ct], acc[ct], 0, 0, 0);
    }
    // C layout 32x32: col = lane&31, row = (reg&3)+8*(reg>>2)+4*(lane>>5)
    const int cbase = w * 64 + (l & 31);
    #pragma unroll
    for (int r = 0; r < 16; ++r) {
        int rl = (r & 3) + 8 * (r >> 2) + 4 * (l >> 5);
        int row = rb + rl;
        #pragma unroll
        for (int ct = 0; ct < 2; ++ct)
            out[(size_t)row * CD + cbase + ct * 32] = acc[ct][r];
    }
}

// ---- fused edge kernel: one (b,i) pair per block, M=64 ----
// R0 body, with phase-3 column softmax replaced by in-register den/num
// accumulation inside the env loop (each lane owns 16 j-rows x 4 cols).
template<bool INBF, bool OUTBF>
__global__ __launch_bounds__(512, 4) void edge_mfma(
    const void* __restrict__ einv, void* __restrict__ eoutv,
    const float* __restrict__ Vix, const float* __restrict__ Vjx,
    const float* __restrict__ Ujx, const unsigned short* __restrict__ Bp,
    const float* __restrict__ ge, const float* __restrict__ be,
    float* __restrict__ agg)
{
    __shared__ unsigned short tile[64 * TPAD];   // 66.6 KB
    __shared__ float sums[64][4][2];             // [row][H-quarter][s1,s2]
    __shared__ float red[4][4][2][2][32];        // [tt][H][stripe][den/num][lane] 8 KB

    const int bi = blockIdx.x;                   // b*64 + i
    const int brow = bi & ~63;                   // b*64
    const int t = threadIdx.x, l = t & 63, w = t >> 6;
    const int stripe = w & 1, H = w >> 1;        // 2 row-stripes x 4 col-quarters

    // ---- stage edge pair -> bf16 LDS ----
    if (INBF) {
        const unsigned short* src = (const unsigned short*)einv + (size_t)bi * 65536;
        #pragma unroll 4
        for (int it = 0; it < 8; ++it) {
            int flat = it * 4096 + t * 8;
            int r = flat >> 9, c = flat & 511;
            *(sv8*)(tile + r * TPAD + c) = *(const sv8*)(src + flat);
        }
    } else {
        const float* src = (const float*)einv + (size_t)bi * 32768;
        #pragma unroll 4
        for (int it = 0; it < 16; ++it) {
            int flat = it * 2048 + t * 4;
            float4 v4 = *(const float4*)(src + flat);
            int r = flat >> 9, c = flat & 511;
            sv4 pk; pk.x = (short)f2bf(v4.x); pk.y = (short)f2bf(v4.y);
            pk.z = (short)f2bf(v4.z); pk.w = (short)f2bf(v4.w);
            *(sv4*)(tile + r * TPAD + c) = pk;
        }
    }
    __syncthreads();

    // ---- K-loop: 32 steps of K=16, zero barriers, B streamed from L2 ----
    f32x16 acc[4] = {};
    const unsigned short* aptr = tile + (size_t)(stripe * 32 + (l & 31)) * TPAD + (l >> 5) * 8;
    const unsigned short* bptr = Bp + ((size_t)(H * 4) * 64 + l) * 8;

    bfrag8 a0, a1, b0[4], b1[4];
    a0 = *(const bfrag8*)aptr;
    #pragma unroll
    for (int tt = 0; tt < 4; ++tt) b0[tt] = *(const bfrag8*)(bptr + tt * 512);
    for (int k2 = 0; k2 < 16; ++k2) {
        int kt1 = 2 * k2 + 1;
        a1 = *(const bfrag8*)(aptr + kt1 * 16);
        #pragma unroll
        for (int tt = 0; tt < 4; ++tt) b1[tt] = *(const bfrag8*)(bptr + (size_t)kt1 * 8192 + tt * 512);
        #pragma unroll
        for (int tt = 0; tt < 4; ++tt)
            acc[tt] = __builtin_amdgcn_mfma_f32_32x32x16_bf16(a0, b0[tt], acc[tt], 0, 0, 0);
        int kt2 = (k2 == 15) ? 31 : (2 * k2 + 2);
        a0 = *(const bfrag8*)(aptr + kt2 * 16);
        #pragma unroll
        for (int tt = 0; tt < 4; ++tt) b0[tt] = *(const bfrag8*)(bptr + (size_t)kt2 * 8192 + tt * 512);
        #pragma unroll
        for (int tt = 0; tt < 4; ++tt)
            acc[tt] = __builtin_amdgcn_mfma_f32_32x32x16_bf16(a1, b1[tt], acc[tt], 0, 0, 0);
    }

    // ---- epilogue: m = acc + vix + vjx; LN partial stats over 128 cols ----
    const int cbase = H * 128 + (l & 31);
    float vix[4], gev[4], bev[4];
    #pragma unroll
    for (int tt = 0; tt < 4; ++tt) {
        int c = cbase + tt * 32;
        vix[tt] = Vix[(size_t)bi * CD + c];
        gev[tt] = ge[c]; bev[tt] = be[c];
    }
    float s1[16], s2[16];
    #pragma unroll
    for (int r = 0; r < 16; ++r) {
        int rl = (r & 3) + 8 * (r >> 2) + 4 * (l >> 5);
        int rt = stripe * 32 + rl;               // row = j in [0,64)
        const float* vjr = Vjx + (size_t)(brow + rt) * CD;
        float a1_ = 0.f, a2_ = 0.f;
        #pragma unroll
        for (int tt = 0; tt < 4; ++tt) {
            float m = acc[tt][r] + vix[tt] + vjr[cbase + tt * 32];
            acc[tt][r] = m;
            a1_ += m; a2_ = fmaf(m, m, a2_);
        }
        s1[r] = a1_; s2[r] = a2_;
    }
    #pragma unroll
    for (int off = 1; off < 32; off <<= 1) {
        #pragma unroll
        for (int r = 0; r < 16; ++r) {
            s1[r] += __shfl_xor(s1[r], off, 64);
            s2[r] += __shfl_xor(s2[r], off, 64);
        }
    }
    if ((l & 31) == 0) {
        #pragma unroll
        for (int r = 0; r < 16; ++r) {
            int rl = (r & 3) + 8 * (r >> 2) + 4 * (l >> 5);
            int rt = stripe * 32 + rl;
            sums[rt][H][0] = s1[r]; sums[rt][H][1] = s2[r];
        }
    }
    __syncthreads();

    // ---- env = edge + relu(LN(m)); write; accumulate softmax den/num in regs ----
    const float* UjxB = Ujx + (size_t)brow * CD;
    float den[4] = {0.f,0.f,0.f,0.f}, num[4] = {0.f,0.f,0.f,0.f};
    #pragma unroll
    for (int r = 0; r < 16; ++r) {
        int rl = (r & 3) + 8 * (r >> 2) + 4 * (l >> 5);
        int rt = stripe * 32 + rl;
        float t1 = sums[rt][0][0] + sums[rt][1][0] + sums[rt][2][0] + sums[rt][3][0];
        float t2 = sums[rt][0][1] + sums[rt][1][1] + sums[rt][2][1] + sums[rt][3][1];
        float mean = t1 * (1.f / 512.f);
        float var  = t2 * (1.f / 512.f) - mean * mean;
        float rs   = rsqrtf(var + 1e-5f);
        const unsigned short* trow = tile + (size_t)rt * TPAD;
        const float* ujr = UjxB + (size_t)rt * CD;
        #pragma unroll
        for (int tt = 0; tt < 4; ++tt) {
            int c = cbase + tt * 32;
            float ln  = (acc[tt][r] - mean) * rs * gev[tt] + bev[tt];
            float env = bf2f(trow[c]) + fmaxf(ln, 0.f);
            if (OUTBF) ((unsigned short*)eoutv)[(size_t)bi * 65536 + rt * 512 + c] = f2bf(env);
            else       ((float*)eoutv)[(size_t)bi * 32768 + rt * 512 + c] = env;
            float sg = 1.f / (1.f + __expf(-env));
            float wv = bf2f(f2bf(__expf(sg)));   // keep bf16 rounding: identical to R0
            den[tt] += wv;
            num[tt] = fmaf(wv, ujr[c], num[tt]);
        }
    }
    // combine hi-halves (lanes l and l^32 own the same columns)
    #pragma unroll
    for (int tt = 0; tt < 4; ++tt) {
        den[tt] += __shfl_xor(den[tt], 32, 64);
        num[tt] += __shfl_xor(num[tt], 32, 64);
    }
    if (l < 32) {
        #pragma unroll
        for (int tt = 0; tt < 4; ++tt) {
            red[tt][H][stripe][0][l] = den[tt];
            red[tt][H][stripe][1][l] = num[tt];
        }
    }
    __syncthreads();

    // ---- cross-stripe combine + agg write (even waves, lanes 0..31) ----
    if (stripe == 0 && l < 32) {
        #pragma unroll
        for (int tt = 0; tt < 4; ++tt) {
            float d  = red[tt][H][0][0][l] + red[tt][H][1][0][l];
            float nm = red[tt][H][0][1][l] + red[tt][H][1][1][l];
            agg[(size_t)bi * CD + H * 128 + l + tt * 32] = nm / (d * (float)NNODE);
        }
    }
}

// ---- x update: x = relu(res + LN(XU + agg)) ----
__global__ __launch_bounds__(256) void xupd_kernel(
    const float* __restrict__ res,
    const float* __restrict__ XU,
    const float* __restrict__ aggp,
    const float* __restrict__ gv, const float* __restrict__ bv,
    float* __restrict__ xout)
{
    int r = blockIdx.x * 4 + (threadIdx.x >> 6);
    int lane = threadIdx.x & 63;
    const float* xu = XU + (size_t)r * CD;
    const float* ag = aggp + (size_t)r * CD;
    float y[8]; float s1 = 0.f, s2 = 0.f;
    #pragma unroll
    for (int u = 0; u < 8; ++u) {
        int c = lane + u * 64;
        float v = xu[c] + ag[c];
        y[u] = v; s1 += v; s2 += v * v;
    }
    #pragma unroll
    for (int off = 32; off > 0; off >>= 1) {
        s1 += __shfl_xor(s1, off, 64);
        s2 += __shfl_xor(s2, off, 64);
    }
    float mean = s1 * (1.f / 512.f);
    float var  = s2 * (1.f / 512.f) - mean * mean;
    float rs   = rsqrtf(var + 1e-5f);
    const float* rr = res + (size_t)r * CD;
    float* xo = xout + (size_t)r * CD;
    #pragma unroll
    for (int u = 0; u < 8; ++u) {
        int c = lane + u * 64;
        float ln = (y[u] - mean) * rs * gv[c] + bv[c];
        xo[c] = fmaxf(rr[c] + ln, 0.f);
    }
}

extern "C" void kernel_launch(void* const* d_in, const int* in_sizes, int n_in,
                              void* d_out, int out_size, void* d_ws, size_t ws_size,
                              hipStream_t stream)
{
    const float* x    = (const float*)d_in[0];
    const float* edge = (const float*)d_in[1];
    const float* W[10];
    for (int i = 0; i < 10; ++i) W[i] = (const float*)d_in[2 + i];
    // 0 WA1, 1 WB1, 2 WE1, 3 WU1, 4 WV1, 5 WA2, 6 WB2, 7 WE2, 8 WU2, 9 WV2
    const float* ge1 = (const float*)d_in[12];
    const float* gv1 = (const float*)d_in[13];
    const float* ge2 = (const float*)d_in[14];
    const float* gv2 = (const float*)d_in[15];
    const float* be1 = (const float*)d_in[16];
    const float* bv1 = (const float*)d_in[17];
    const float* be2 = (const float*)d_in[18];
    const float* bv2 = (const float*)d_in[19];

    char* wsb = (char*)d_ws;
    unsigned short* P32 = (unsigned short*)wsb;               // 10 x 512 KB = 5 MB
    float* Vix = (float*)(wsb + (size_t)6  * 1048576);
    float* Vjx = (float*)(wsb + (size_t)8  * 1048576);
    float* Ujx = (float*)(wsb + (size_t)10 * 1048576);
    float* XUa = (float*)(wsb + (size_t)12 * 1048576);
    float* agg = (float*)(wsb + (size_t)14 * 1048576);
    float* x1  = (float*)(wsb + (size_t)16 * 1048576);
    float* XUb = (float*)(wsb + (size_t)18 * 1048576);

    float* xout  = (float*)d_out;
    float* eintF = xout + (size_t)524288;     // edge region (bf16 lives in slot's first half)

    // pack order: 0 WA1, 1 WB1, 2 WV1, 3 WU1, 4 WA2, 5 WB2, 6 WV2, 7 WU2, 8 WE1, 9 WE2
    pack32_k<<<dim3(32, 16, 10), 64, 0, stream>>>(
        W[0], W[1], W[4], W[3], W[5], W[6], W[9], W[8], W[2], W[7], P32);

#define PW(i) (P32 + (size_t)(i) * 262144)
    // ---- layer 1 ----
    proj_mfma<false><<<dim3(32, 4), 512, 0, stream>>>(x, PW(0), Vix, Vjx, Ujx, XUa,
                                                      nullptr, nullptr, nullptr, nullptr, nullptr);
    edge_mfma<false, true><<<1024, 512, 0, stream>>>(edge, eintF, Vix, Vjx, Ujx,
                                                     PW(8), ge1, be1, agg);
    // ---- layer 2 (proj stage fuses x1 = relu(x + LN(XUa + agg))) ----
    proj_mfma<true><<<dim3(32, 4), 512, 0, stream>>>(XUa, PW(4), Vix, Vjx, Ujx, XUb,
                                                     agg, x, gv1, bv1, x1);
    edge_mfma<true, false><<<1024, 512, 0, stream>>>(eintF, eintF, Vix, Vjx, Ujx,
                                                     PW(9), ge2, be2, agg);
    xupd_kernel<<<256, 256, 0, stream>>>(x1, XUb, agg, gv2, bv2, xout);
#undef PW
}